// Round 2
// baseline (7326.314 us; speedup 1.0000x reference)
//
#include <hip/hip_runtime.h>

// Decoder with Bahdanau attention, B=16, T=64, S=128, D_ENC=512, U=256, V=32000.
// Strategy: 2 kernels per step (Z gemm + fused gates/vocab/attention), bf16 Wd,
// unnormalized exp + deferred softmax scale.

#define NB 16
#define NT 64
#define NS 128
#define DE 512
#define NU 256
#define NV 32000
#define HSS 20   // LDS stride for h_new[u][b] layout (16B aligned, few bank conflicts)

static const size_t OFF_KEYS = 0;                       // 16*128*256
static const size_t OFF_H    = 524288;                  // 2*16*256
static const size_t OFF_C    = OFF_H + 2 * NB * NU;     // 2*16*256
static const size_t OFF_X    = OFF_C + 2 * NB * NU;     // 16*768
static const size_t OFF_Z    = OFF_X + NB * 768;        // 2*16*1024
static const size_t OFF_RS   = OFF_Z + 2 * NB * 1024;   // 64*16
static const size_t OFF_WD   = OFF_RS + NT * NB;        // 256*32000 ushorts = 4.096M floats
static const size_t WS_FLOATS = OFF_WD + (size_t)NU * NV / 2;

__device__ __forceinline__ float bf2f(unsigned int us) {
    return __uint_as_float(us << 16);
}
__device__ __forceinline__ unsigned short f2bf(float f) {
    unsigned int u = __float_as_uint(f);
    return (unsigned short)((u + 0x7fffu + ((u >> 16) & 1u)) >> 16);
}
__device__ __forceinline__ float rcp_fast(float x) {
    return __builtin_amdgcn_rcpf(x);
}
__device__ __forceinline__ float sigm(float x) {
    return rcp_fast(1.0f + __expf(-x));
}
__device__ __forceinline__ float tanh1(float x) {
    // 1 - 2/(e^{2x}+1): monotone, saturates correctly at +/-inf, no NaN.
    float e = __expf(2.0f * x);
    return 1.0f - 2.0f * rcp_fast(e + 1.0f);
}

// ---------------- keys = enc @ W2 + b2 ----------------
__launch_bounds__(256)
__global__ void keys_kernel(const float* __restrict__ enc, const float* __restrict__ W2,
                            const float* __restrict__ b2, float* __restrict__ keys) {
    int b = blockIdx.x >> 4, so = blockIdx.x & 15;  // 16 chunks of 8 s-rows
    int u = threadIdx.x;
    float acc[8];
    float bias = b2[u];
#pragma unroll
    for (int ss = 0; ss < 8; ss++) acc[ss] = bias;
    const float* eb = enc + ((size_t)b * NS + so * 8) * DE;
#pragma unroll 2
    for (int d = 0; d < DE; d++) {
        float w = W2[d * NU + u];
#pragma unroll
        for (int ss = 0; ss < 8; ss++) acc[ss] += eb[ss * DE + d] * w;  // uniform -> s_load
    }
    float* kb = keys + ((size_t)b * NS + so * 8) * NU;
#pragma unroll
    for (int ss = 0; ss < 8; ss++) kb[ss * NU + u] = acc[ss];
}

// ---------------- Wd fp32 -> bf16 ----------------
__launch_bounds__(256)
__global__ void wdcast_kernel(const float* __restrict__ Wd, unsigned short* __restrict__ wd16) {
    size_t i = ((size_t)blockIdx.x * 256 + threadIdx.x) * 4;
    float4 v = *(const float4*)(Wd + i);
    unsigned int lo = (unsigned int)f2bf(v.x) | ((unsigned int)f2bf(v.y) << 16);
    unsigned int hi = (unsigned int)f2bf(v.z) | ((unsigned int)f2bf(v.w) << 16);
    *(uint2*)(wd16 + i) = make_uint2(lo, hi);
}

// ---------------- attention for one batch row ----------------
template <int HSTRIDE>
__device__ __forceinline__ void att_block(
    int b, int t_att, const float* hvec,  // element d at hvec[d*HSTRIDE]
    const float* __restrict__ keys, const float* __restrict__ enc,
    const int* __restrict__ dec, const float* __restrict__ emb,
    const float* __restrict__ W1, const float* __restrict__ b1,
    const float* __restrict__ Va, const float* __restrict__ bVp,
    float* __restrict__ xb,
    float* q_s, float* scp, float* red, float* attn_s) {
    const int tid = threadIdx.x;
    // q = h @ W1 + b1
    float acc = b1[tid];
#pragma unroll 4
    for (int d = 0; d < NU; d++) acc += hvec[d * HSTRIDE] * W1[d * NU + tid];
    q_s[tid] = acc;
    __syncthreads();
    // scores: 256 threads = 128 s-rows x 2 half-dots
    int s = tid & 127, half = tid >> 7;
    const float* krow = keys + ((size_t)b * NS + s) * NU + half * 128;
    const float* qrow = q_s + half * 128;
    const float* va = Va + half * 128;
    float sc = 0.f;
#pragma unroll 4
    for (int uu = 0; uu < 128; uu++) sc += tanh1(qrow[uu] + krow[uu]) * va[uu];
    scp[half * NS + s] = sc;
    __syncthreads();
    float scfull = 0.f;
    if (tid < NS) {
        scfull = scp[tid] + scp[NS + tid] + bVp[0];
        red[tid] = scfull;
    }
    __syncthreads();
    for (int off = 64; off >= 1; off >>= 1) {
        if (tid < off) red[tid] = fmaxf(red[tid], red[tid + off]);
        __syncthreads();
    }
    float m = red[0];
    __syncthreads();
    float p = 0.f;
    if (tid < NS) {
        p = __expf(scfull - m);
        red[tid] = p;
    }
    __syncthreads();
    for (int off = 64; off >= 1; off >>= 1) {
        if (tid < off) red[tid] += red[tid + off];
        __syncthreads();
    }
    float tot = red[0];
    if (tid < NS) attn_s[tid] = p / tot;
    __syncthreads();
    // ctx = attn @ enc  (512 dims, 2 per thread)
    float c0 = 0.f, c1 = 0.f;
    const float* eb = enc + (size_t)b * NS * DE;
#pragma unroll 2
    for (int ss = 0; ss < NS; ss++) {
        float a = attn_s[ss];
        c0 += a * eb[ss * DE + tid];
        c1 += a * eb[ss * DE + 256 + tid];
    }
    float* xrow = xb + b * 768;
    xrow[tid] = c0;
    xrow[256 + tid] = c1;
    int tok = dec[b * NT + t_att];
    tok = (tok < 0) ? 0 : (tok >= NV ? NV - 1 : tok);  // defensive clamp
    xrow[512 + tid] = emb[(size_t)tok * NU + tid];
}

// ---------------- prologue: attention for t=0 + state init ----------------
__launch_bounds__(256)
__global__ void att0_kernel(const float* __restrict__ h0, const float* __restrict__ c0,
                            const int* __restrict__ dec, const float* __restrict__ emb,
                            const float* __restrict__ W1, const float* __restrict__ b1,
                            const float* __restrict__ Va, const float* __restrict__ bVp,
                            const float* __restrict__ enc, const float* __restrict__ keys,
                            float* __restrict__ ws_x, float* __restrict__ ws_h,
                            float* __restrict__ ws_c, float* __restrict__ ws_z,
                            float* __restrict__ rs, const float* __restrict__ b_lstm) {
    __shared__ float h_loc[NU];
    __shared__ float q_s[NU];
    __shared__ float scp[2 * NS];
    __shared__ float red[NS];
    __shared__ float attn_s[NS];
    int b = blockIdx.x, tid = threadIdx.x;
    float hv = h0[b * NU + tid];
    h_loc[tid] = hv;
    ws_h[b * NU + tid] = hv;            // h[par=0]
    ws_c[b * NU + tid] = c0[b * NU + tid];  // c[par=0]
    if (tid < NT) rs[tid * NB + b] = 0.f;
    // z[0] := b_lstm (atomicAdd accumulates on top)
    float* zn = ws_z + b * 1024;
    zn[tid] = b_lstm[tid];
    zn[256 + tid] = b_lstm[256 + tid];
    zn[512 + tid] = b_lstm[512 + tid];
    zn[768 + tid] = b_lstm[768 + tid];
    __syncthreads();
    att_block<1>(b, 0, h_loc, keys, enc, dec, emb, W1, b1, Va, bVp, ws_x, q_s, scp, red, attn_s);
}

// ---------------- z(t) += [x|h] @ [Wx;Wh]  (k-split, atomic) ----------------
__launch_bounds__(256)
__global__ void z_kernel(int t, const float* __restrict__ Wx, const float* __restrict__ Wh,
                         const float* __restrict__ ws_x, const float* __restrict__ ws_h,
                         float* __restrict__ ws_z) {
    int par = t & 1;
    int jc = blockIdx.x & 15, kq = blockIdx.x >> 4;  // 16 j-chunks x 4 k-quarters
    int jl = threadIdx.x & 63, bq = threadIdx.x >> 6;
    int j = jc * 64 + jl;
    int bqw = __builtin_amdgcn_readfirstlane(bq);  // wave-uniform -> scalar x loads
    const float* Wsrc;
    const float* xsrc;
    int xstride;
    if (kq < 3) {
        Wsrc = Wx + (size_t)kq * 256 * 1024;
        xsrc = ws_x + kq * 256;
        xstride = 768;
    } else {
        Wsrc = Wh;
        xsrc = ws_h + par * NB * NU;
        xstride = NU;
    }
    float a0 = 0.f, a1 = 0.f, a2 = 0.f, a3 = 0.f;
#pragma unroll 4
    for (int kk = 0; kk < 256; kk++) {
        float w = Wsrc[kk * 1024 + j];
        a0 += xsrc[(bqw * 4 + 0) * xstride + kk] * w;
        a1 += xsrc[(bqw * 4 + 1) * xstride + kk] * w;
        a2 += xsrc[(bqw * 4 + 2) * xstride + kk] * w;
        a3 += xsrc[(bqw * 4 + 3) * xstride + kk] * w;
    }
    float* z = ws_z + par * NB * 1024;
    atomicAdd(&z[(bqw * 4 + 0) * 1024 + j], a0);
    atomicAdd(&z[(bqw * 4 + 1) * 1024 + j], a1);
    atomicAdd(&z[(bqw * 4 + 2) * 1024 + j], a2);
    atomicAdd(&z[(bqw * 4 + 3) * 1024 + j], a3);
}

// ---------------- fused: gates (redundant per block) + vocab exp + next attention ----------------
template <typename WT>
__launch_bounds__(256)
__global__ void step_kernel(int t, const WT* __restrict__ Wd,
                            float* __restrict__ ws_z, float* __restrict__ ws_c,
                            float* __restrict__ ws_h, float* __restrict__ ws_x,
                            const float* __restrict__ keys, float* __restrict__ rs,
                            const float* __restrict__ enc, const int* __restrict__ dec,
                            const float* __restrict__ emb, const float* __restrict__ W1,
                            const float* __restrict__ b1, const float* __restrict__ Va,
                            const float* __restrict__ bVp, const float* __restrict__ b_lstm,
                            const float* __restrict__ bd, float* __restrict__ out) {
    __shared__ float hs[NU * HSS];
    __shared__ float vred[3 * 64 * 36];
    __shared__ float q_s[NU];
    __shared__ float scp[2 * NS];
    __shared__ float red[NS];
    __shared__ float attn_s[NS];

    int par = t & 1;
    const float* zb = ws_z + par * NB * 1024;
    const float* cb = ws_c + par * NB * NU;
    float* cnb = ws_c + (par ^ 1) * NB * NU;
    float* hnb = ws_h + (par ^ 1) * NB * NU;
    int u = threadIdx.x;

    // Phase A: gates (every block; z is tiny). h_new -> LDS as [u][b], stride HSS.
#pragma unroll 4
    for (int b = 0; b < NB; b++) {
        float zi = zb[b * 1024 + u];
        float zf = zb[b * 1024 + 256 + u];
        float zg = zb[b * 1024 + 512 + u];
        float zo = zb[b * 1024 + 768 + u];
        float co = cb[b * NU + u];
        float cn = sigm(zf) * co + sigm(zi) * tanh1(zg);
        float hn = sigm(zo) * tanh1(cn);
        hs[u * HSS + b] = hn;
        if (blockIdx.x == 0) {
            hnb[b * NU + u] = hn;
            cnb[b * NU + u] = cn;
        }
    }
    __syncthreads();

    if (blockIdx.x < 250) {
        // vocab: 128 cols/block, 2 cols/thread, 4-way u-split
        int ug = threadIdx.x >> 6;  // 0..3 -> u range of 64
        int cl = threadIdx.x & 63;
        int v0 = blockIdx.x * 128 + cl * 2;
        const WT* wp = Wd + (size_t)(ug * 64) * NV + v0;
        float acc[16][2];
#pragma unroll
        for (int b = 0; b < 16; b++) { acc[b][0] = 0.f; acc[b][1] = 0.f; }
        const float* hbase = &hs[(ug * 64) * HSS];
        for (int uu = 0; uu < 64; uu++) {
            float w0, w1;
            if constexpr (sizeof(WT) == 2) {
                unsigned int ww = *(const unsigned int*)wp;
                w0 = bf2f(ww & 0xffffu);
                w1 = bf2f(ww >> 16);
            } else {
                float2 wv = *(const float2*)wp;
                w0 = wv.x;
                w1 = wv.y;
            }
            const float* hp = hbase + uu * HSS;
            float4 ha = *(const float4*)(hp);
            float4 hb = *(const float4*)(hp + 4);
            float4 hc = *(const float4*)(hp + 8);
            float4 hd = *(const float4*)(hp + 12);
            float hv[16] = {ha.x, ha.y, ha.z, ha.w, hb.x, hb.y, hb.z, hb.w,
                            hc.x, hc.y, hc.z, hc.w, hd.x, hd.y, hd.z, hd.w};
#pragma unroll
            for (int b = 0; b < 16; b++) {
                acc[b][0] += hv[b] * w0;
                acc[b][1] += hv[b] * w1;
            }
            wp += NV;
        }
        if (ug > 0) {
            float* dst = &vred[(ug - 1) * 64 * 36 + cl * 36];
#pragma unroll
            for (int b = 0; b < 16; b++) {
                dst[b * 2] = acc[b][0];
                dst[b * 2 + 1] = acc[b][1];
            }
        }
        __syncthreads();
        if (ug == 0) {
#pragma unroll
            for (int g = 0; g < 3; g++) {
                const float* src = &vred[g * 64 * 36 + cl * 36];
#pragma unroll
                for (int b = 0; b < 16; b++) {
                    acc[b][0] += src[b * 2];
                    acc[b][1] += src[b * 2 + 1];
                }
            }
            float2 bd2 = *(const float2*)(bd + v0);
#pragma unroll
            for (int b = 0; b < 16; b++) {
                float p0 = __expf(acc[b][0] + bd2.x);
                float p1 = __expf(acc[b][1] + bd2.y);
                *(float2*)(out + (size_t)(b * NT + t) * NV + v0) = make_float2(p0, p1);
                float s = p0 + p1;
#pragma unroll
                for (int off = 32; off >= 1; off >>= 1) s += __shfl_xor(s, off, 64);
                if (cl == 0) atomicAdd(&rs[t * NB + b], s);
            }
        }
    } else if (t + 1 < NT) {
        // next-step attention + init z[par^1] with b_lstm
        int b = blockIdx.x - 250;
        float* zn = ws_z + (par ^ 1) * NB * 1024 + b * 1024;
        zn[u] = b_lstm[u];
        zn[256 + u] = b_lstm[256 + u];
        zn[512 + u] = b_lstm[512 + u];
        zn[768 + u] = b_lstm[768 + u];
        att_block<HSS>(b, t + 1, &hs[b], keys, enc, dec, emb, W1, b1, Va, bVp, ws_x,
                       q_s, scp, red, attn_s);
    }
}

// ---------------- final softmax normalization ----------------
__launch_bounds__(256)
__global__ void scale_kernel(float* __restrict__ out, const float* __restrict__ rs) {
    int blk = blockIdx.x;       // blk = b*64 + t  == row index of out
    int b = blk >> 6, t = blk & 63;
    float rinv = 1.0f / rs[t * NB + b];
    float* o = out + (size_t)blk * NV;
    for (int i = threadIdx.x; i < NV; i += 256) o[i] *= rinv;
}

extern "C" void kernel_launch(void* const* d_in, const int* in_sizes, int n_in,
                              void* d_out, int out_size, void* d_ws, size_t ws_size,
                              hipStream_t stream) {
    const int* dec = (const int*)d_in[0];
    const float* enc = (const float*)d_in[1];
    const float* h0 = (const float*)d_in[2];
    const float* c0 = (const float*)d_in[3];
    const float* emb = (const float*)d_in[4];
    const float* W1 = (const float*)d_in[5];
    const float* b1 = (const float*)d_in[6];
    const float* W2 = (const float*)d_in[7];
    const float* b2 = (const float*)d_in[8];
    const float* Va = (const float*)d_in[9];
    const float* bV = (const float*)d_in[10];
    const float* Wx = (const float*)d_in[11];
    const float* Wh = (const float*)d_in[12];
    const float* b_lstm = (const float*)d_in[13];
    const float* Wd = (const float*)d_in[14];
    const float* bd = (const float*)d_in[15];
    float* out = (float*)d_out;
    float* ws = (float*)d_ws;

    float* ws_keys = ws + OFF_KEYS;
    float* ws_h = ws + OFF_H;
    float* ws_c = ws + OFF_C;
    float* ws_x = ws + OFF_X;
    float* ws_z = ws + OFF_Z;
    float* ws_rs = ws + OFF_RS;
    unsigned short* wd16 = (unsigned short*)(ws + OFF_WD);

    bool use_bf16 = ws_size >= WS_FLOATS * sizeof(float);

    keys_kernel<<<256, 256, 0, stream>>>(enc, W2, b2, ws_keys);
    if (use_bf16) wdcast_kernel<<<8000, 256, 0, stream>>>(Wd, wd16);
    att0_kernel<<<16, 256, 0, stream>>>(h0, c0, dec, emb, W1, b1, Va, bV, enc, ws_keys,
                                        ws_x, ws_h, ws_c, ws_z, ws_rs, b_lstm);
    for (int t = 0; t < NT; t++) {
        z_kernel<<<64, 256, 0, stream>>>(t, Wx, Wh, ws_x, ws_h, ws_z);
        if (use_bf16)
            step_kernel<unsigned short><<<266, 256, 0, stream>>>(
                t, wd16, ws_z, ws_c, ws_h, ws_x, ws_keys, ws_rs, enc, dec, emb, W1, b1,
                Va, bV, b_lstm, bd, out);
        else
            step_kernel<float><<<266, 256, 0, stream>>>(
                t, Wd, ws_z, ws_c, ws_h, ws_x, ws_keys, ws_rs, enc, dec, emb, W1, b1,
                Va, bV, b_lstm, bd, out);
    }
    scale_kernel<<<1024, 256, 0, stream>>>(out, ws_rs);
}

// Round 3
// 6846.887 us; speedup vs baseline: 1.0700x; 1.0700x over previous
//
#include <hip/hip_runtime.h>

// Decoder, B=16, T=64, S=128, D_ENC=512, U=256, V=32000.
// Round 2: hoist vocab projection out of the sequential loop.
//   per step: R1 = attention (16 blocks), R2 = LSTM z+gates (64 blocks)
//   epilogue: one bf16 MFMA GEMM H[1024x256] @ Wd[256x32000] + exp + rowsum,
//             then deferred softmax scale.
// Wd and H are stored in MFMA-fragment-tiled layout so the GEMM needs no LDS.

#define NB 16
#define NT 64
#define NS 128
#define DE 512
#define NU 256
#define NV 32000

// ws layout (floats)
static const size_t OFF_KEYS = 0;              // bf16 keys 16*128*256 -> 262144 floats
static const size_t OFF_XT   = 262144;         // xT[1280][16] fp32 (x rows 0..767, h dbuf 768..1279)
static const size_t OFF_H    = OFF_XT + 20480;   // h[16][256]
static const size_t OFF_C    = OFF_H + 4096;     // c[16][256]
static const size_t OFF_RS   = OFF_C + 4096;     // rowsums[1024]
static const size_t OFF_HBUF = OFF_RS + 1024;    // H tiled bf16: 8 panels * 32768 -> 131072 floats
static const size_t OFF_WDT  = OFF_HBUF + 131072; // Wd tiled bf16: 1024000*16B -> 4096000 floats
// total = 4,518,912 floats = 18.08 MB (<= 18.73 MB proven available)

typedef __attribute__((ext_vector_type(8))) short bf16x8;
typedef __attribute__((ext_vector_type(4))) float f32x4;

__device__ __forceinline__ float bf2f(unsigned int us) {
    return __uint_as_float(us << 16);
}
__device__ __forceinline__ unsigned short f2bf(float f) {
    unsigned int u = __float_as_uint(f);
    return (unsigned short)((u + 0x7fffu + ((u >> 16) & 1u)) >> 16);
}
__device__ __forceinline__ float rcp_fast(float x) { return __builtin_amdgcn_rcpf(x); }
__device__ __forceinline__ float sigm(float x) { return rcp_fast(1.0f + __expf(-x)); }
__device__ __forceinline__ float tanh1(float x) {
    float e = __expf(2.0f * x);
    return 1.0f - 2.0f * rcp_fast(e + 1.0f);
}

// ---------------- init: seed h, c, xT h-rows, zero rowsums ----------------
__launch_bounds__(256)
__global__ void init_kernel(const float* __restrict__ h0, const float* __restrict__ c0,
                            float* __restrict__ ws_h, float* __restrict__ ws_c,
                            float* __restrict__ xT, float* __restrict__ rs) {
    int b = blockIdx.x, u = threadIdx.x;
    float hv = h0[b * NU + u];
    ws_h[b * NU + u] = hv;
    ws_c[b * NU + u] = c0[b * NU + u];
    xT[(768 + u) * NB + b] = hv;  // par=0 h rows
    if (u < 64) rs[b * 64 + u] = 0.f;
}

// ---------------- keys = enc @ W2 + b2 (bf16 out) ----------------
__launch_bounds__(256)
__global__ void keys_kernel(const float* __restrict__ enc, const float* __restrict__ W2,
                            const float* __restrict__ b2, unsigned short* __restrict__ keys16) {
    __shared__ float els[8 * DE];  // 16 KB
    int b = blockIdx.x >> 4, so = blockIdx.x & 15;
    int u = threadIdx.x;
    const float4* src = (const float4*)(enc + ((size_t)b * NS + so * 8) * DE);
    float4* dst = (float4*)els;
    for (int i = u; i < 8 * DE / 4; i += 256) dst[i] = src[i];
    __syncthreads();
    float bias = b2[u];
    float acc[8];
#pragma unroll
    for (int ss = 0; ss < 8; ss++) acc[ss] = bias;
#pragma unroll 4
    for (int d = 0; d < DE; d++) {
        float w = W2[d * NU + u];
#pragma unroll
        for (int ss = 0; ss < 8; ss++) acc[ss] = fmaf(els[ss * DE + d], w, acc[ss]);
    }
    unsigned short* kb = keys16 + ((size_t)b * NS + so * 8) * NU;
#pragma unroll
    for (int ss = 0; ss < 8; ss++) kb[ss * NU + u] = f2bf(acc[ss]);
}

// ---------------- Wd -> fragment-tiled bf16 ----------------
// chunk id = ((p*8 + ks)*8 + c16)*64 + l ; 16B chunk = 8 bf16 along k.
// element j of chunk: Wd[k0+j][v], k0 = ks*32 + (l>>4)*8, v = p*128 + c16*16 + (l&15)
__launch_bounds__(256)
__global__ void wdtile_kernel(const float* __restrict__ Wd, unsigned short* __restrict__ wdT) {
    int id = blockIdx.x * 256 + threadIdx.x;  // 0 .. 1,023,999
    int l = id & 63, c16 = (id >> 6) & 7, ks = (id >> 9) & 7, p = id >> 12;
    int v = p * 128 + c16 * 16 + (l & 15);
    int k0 = ks * 32 + (l >> 4) * 8;
    unsigned int wout[4];
#pragma unroll
    for (int jj = 0; jj < 4; jj++) {
        unsigned int lo = f2bf(Wd[(size_t)(k0 + 2 * jj) * NV + v]);
        unsigned int hi = f2bf(Wd[(size_t)(k0 + 2 * jj + 1) * NV + v]);
        wout[jj] = lo | (hi << 16);
    }
    *(uint4*)(wdT + (size_t)id * 8) = make_uint4(wout[0], wout[1], wout[2], wout[3]);
}

// ---------------- R1: attention for step t (one block per b) ----------------
__launch_bounds__(256)
__global__ void att_kernel(int t, const int* __restrict__ dec, const float* __restrict__ emb,
                           const float* __restrict__ W1, const float* __restrict__ b1,
                           const float* __restrict__ Va, const float* __restrict__ bVp,
                           const float* __restrict__ enc, const unsigned short* __restrict__ keys16,
                           const float* __restrict__ ws_h, float* __restrict__ xT) {
    __shared__ float hl[NU];
    __shared__ float q_s[NU];
    __shared__ float scp[NU];
    __shared__ float red[NS];
    __shared__ float attn_s[NS];
    int b = blockIdx.x, tid = threadIdx.x;
    hl[tid] = ws_h[b * NU + tid];
    __syncthreads();
    // q = h @ W1 + b1
    float acc = b1[tid];
#pragma unroll 4
    for (int d = 0; d < NU; d++) acc = fmaf(hl[d], W1[d * NU + tid], acc);
    q_s[tid] = acc;
    __syncthreads();
    // scores
    int s = tid & 127, half = tid >> 7;
    const unsigned int* krow =
        (const unsigned int*)(keys16 + ((size_t)b * NS + s) * NU + half * 128);
    const float* qrow = q_s + half * 128;
    const float* va = Va + half * 128;
    float sc = 0.f;
#pragma unroll 4
    for (int uu = 0; uu < 64; uu++) {
        unsigned int kk = krow[uu];
        sc = fmaf(tanh1(qrow[2 * uu] + bf2f(kk & 0xffffu)), va[2 * uu], sc);
        sc = fmaf(tanh1(qrow[2 * uu + 1] + bf2f(kk >> 16)), va[2 * uu + 1], sc);
    }
    scp[half * NS + s] = sc;
    __syncthreads();
    float scfull = 0.f;
    if (tid < NS) {
        scfull = scp[tid] + scp[NS + tid] + bVp[0];
        red[tid] = scfull;
    }
    __syncthreads();
    for (int off = 64; off >= 1; off >>= 1) {
        if (tid < off) red[tid] = fmaxf(red[tid], red[tid + off]);
        __syncthreads();
    }
    float m = red[0];
    __syncthreads();
    float p = 0.f;
    if (tid < NS) {
        p = __expf(scfull - m);
        red[tid] = p;
    }
    __syncthreads();
    for (int off = 64; off >= 1; off >>= 1) {
        if (tid < off) red[tid] += red[tid + off];
        __syncthreads();
    }
    float tot = red[0];
    if (tid < NS) attn_s[tid] = p / tot;
    __syncthreads();
    // ctx
    float c0 = 0.f, c1 = 0.f;
    const float* eb = enc + (size_t)b * NS * DE;
#pragma unroll 2
    for (int ss = 0; ss < NS; ss++) {
        float a = attn_s[ss];
        c0 = fmaf(a, eb[ss * DE + tid], c0);
        c1 = fmaf(a, eb[ss * DE + 256 + tid], c1);
    }
    xT[tid * NB + b] = c0;
    xT[(256 + tid) * NB + b] = c1;
    int tok = dec[b * NT + t];
    tok = (tok < 0) ? 0 : (tok >= NV ? NV - 1 : tok);
    xT[(512 + tid) * NB + b] = emb[(size_t)tok * NU + tid];
}

// ---------------- R2: z = x@Wx + h@Wh + b ; gates ; write h ----------------
__launch_bounds__(256)
__global__ void lstm_kernel(int t, const float* __restrict__ Wx, const float* __restrict__ Wh,
                            const float* __restrict__ b_lstm, float* __restrict__ xT,
                            float* __restrict__ ws_h, float* __restrict__ ws_c,
                            unsigned short* __restrict__ Hb) {
    __shared__ float zsh[16][17];
    int blk = blockIdx.x, tid = threadIdx.x;
    int b = tid >> 4, jl = tid & 15;
    int g = jl >> 2, ul = jl & 3;
    int u = blk * 4 + ul;
    int j = g * 256 + u;
    int par = t & 1;

    float a0 = 0.f, a1 = 0.f, a2 = 0.f, a3 = 0.f;
    const float* __restrict__ wp = Wx + j;
#pragma unroll 4
    for (int k = 0; k < 768; k += 4) {
        a0 = fmaf(wp[(size_t)(k + 0) * 1024], xT[(k + 0) * NB + b], a0);
        a1 = fmaf(wp[(size_t)(k + 1) * 1024], xT[(k + 1) * NB + b], a1);
        a2 = fmaf(wp[(size_t)(k + 2) * 1024], xT[(k + 2) * NB + b], a2);
        a3 = fmaf(wp[(size_t)(k + 3) * 1024], xT[(k + 3) * NB + b], a3);
    }
    const float* __restrict__ wh = Wh + j;
    const float* __restrict__ xh = xT + (768 + par * 256) * NB;
#pragma unroll 4
    for (int k = 0; k < 256; k += 4) {
        a0 = fmaf(wh[(size_t)(k + 0) * 1024], xh[(k + 0) * NB + b], a0);
        a1 = fmaf(wh[(size_t)(k + 1) * 1024], xh[(k + 1) * NB + b], a1);
        a2 = fmaf(wh[(size_t)(k + 2) * 1024], xh[(k + 2) * NB + b], a2);
        a3 = fmaf(wh[(size_t)(k + 3) * 1024], xh[(k + 3) * NB + b], a3);
    }
    zsh[jl][b] = (a0 + a1) + (a2 + a3);
    __syncthreads();

    if (tid < 64) {
        int b2 = tid & 15, ul2 = tid >> 4;
        int u2 = blk * 4 + ul2;
        float zi = zsh[0 + ul2][b2] + b_lstm[u2];
        float zf = zsh[4 + ul2][b2] + b_lstm[256 + u2];
        float zg = zsh[8 + ul2][b2] + b_lstm[512 + u2];
        float zo = zsh[12 + ul2][b2] + b_lstm[768 + u2];
        float c = ws_c[b2 * NU + u2];
        float cn = sigm(zf) * c + sigm(zi) * tanh1(zg);
        float hn = sigm(zo) * tanh1(cn);
        ws_c[b2 * NU + u2] = cn;
        ws_h[b2 * NU + u2] = hn;
        xT[(768 + (par ^ 1) * 256 + u2) * NB + b2] = hn;
        // fragment-tiled Hbuf write
        int r = t * NB + b2;
        int mp = r >> 7, lr = r & 127;
        int chunk = ((u2 >> 5) * 8 + (lr >> 4)) * 64 + ((u2 >> 3) & 3) * 16 + (lr & 15);
        Hb[(size_t)mp * 32768 + chunk * 8 + (u2 & 7)] = f2bf(hn);
    }
}

// ---------------- batched vocab GEMM + exp + rowsum ----------------
__launch_bounds__(256)
__global__ void gemm_kernel(const unsigned short* __restrict__ Hb,
                            const unsigned short* __restrict__ wdT,
                            const float* __restrict__ bd, float* __restrict__ out,
                            float* __restrict__ rs) {
    // XCD-contiguous work mapping (2000 % 8 == 0)
    int w = (blockIdx.x & 7) * 250 + (blockIdx.x >> 3);
    int np = w >> 3, mp = w & 7;
    int wave = threadIdx.x >> 6, l = threadIdx.x & 63;
    int wm = wave >> 1, wn = wave & 1;
    const bf16x8* A = (const bf16x8*)Hb + (size_t)mp * 4096;
    const bf16x8* B = (const bf16x8*)wdT + (size_t)np * 4096;
    f32x4 acc[4][4];
#pragma unroll
    for (int mf = 0; mf < 4; mf++)
#pragma unroll
        for (int nf = 0; nf < 4; nf++) acc[mf][nf] = (f32x4){0.f, 0.f, 0.f, 0.f};
#pragma unroll
    for (int ks = 0; ks < 8; ks++) {
        bf16x8 av[4], bv[4];
#pragma unroll
        for (int mf = 0; mf < 4; mf++) av[mf] = A[(ks * 8 + wm * 4 + mf) * 64 + l];
#pragma unroll
        for (int nf = 0; nf < 4; nf++) bv[nf] = B[(ks * 8 + wn * 4 + nf) * 64 + l];
#pragma unroll
        for (int mf = 0; mf < 4; mf++)
#pragma unroll
            for (int nf = 0; nf < 4; nf++)
                acc[mf][nf] =
                    __builtin_amdgcn_mfma_f32_16x16x32_bf16(av[mf], bv[nf], acc[mf][nf], 0, 0, 0);
    }
    int colg = np * 128 + wn * 64;
    int rowg = mp * 128 + wm * 64;
#pragma unroll
    for (int mf = 0; mf < 4; mf++) {
        float rloc[4] = {0.f, 0.f, 0.f, 0.f};
#pragma unroll
        for (int nf = 0; nf < 4; nf++) {
            int col = colg + nf * 16 + (l & 15);
            float bdv = bd[col];
#pragma unroll
            for (int reg = 0; reg < 4; reg++) {
                int r = rowg + mf * 16 + (l >> 4) * 4 + reg;  // r = t*16 + b
                float p = __expf(acc[mf][nf][reg] + bdv);
                out[(size_t)((r & 15) * NT + (r >> 4)) * NV + col] = p;
                rloc[reg] += p;
            }
        }
#pragma unroll
        for (int reg = 0; reg < 4; reg++) {
            float v = rloc[reg];
            v += __shfl_xor(v, 1);
            v += __shfl_xor(v, 2);
            v += __shfl_xor(v, 4);
            v += __shfl_xor(v, 8);
            if ((l & 15) == 0) atomicAdd(&rs[rowg + mf * 16 + (l >> 4) * 4 + reg], v);
        }
    }
}

// ---------------- final softmax normalization ----------------
__launch_bounds__(256)
__global__ void scale_kernel(float* __restrict__ out, const float* __restrict__ rs) {
    int o = blockIdx.x;  // out row = b*64 + t
    int b = o >> 6, t = o & 63;
    float rinv = 1.0f / rs[t * NB + b];
    float4* op = (float4*)(out + (size_t)o * NV);
    for (int i = threadIdx.x; i < NV / 4; i += 256) {
        float4 v = op[i];
        v.x *= rinv; v.y *= rinv; v.z *= rinv; v.w *= rinv;
        op[i] = v;
    }
}

extern "C" void kernel_launch(void* const* d_in, const int* in_sizes, int n_in,
                              void* d_out, int out_size, void* d_ws, size_t ws_size,
                              hipStream_t stream) {
    const int* dec = (const int*)d_in[0];
    const float* enc = (const float*)d_in[1];
    const float* h0 = (const float*)d_in[2];
    const float* c0 = (const float*)d_in[3];
    const float* emb = (const float*)d_in[4];
    const float* W1 = (const float*)d_in[5];
    const float* b1 = (const float*)d_in[6];
    const float* W2 = (const float*)d_in[7];
    const float* b2 = (const float*)d_in[8];
    const float* Va = (const float*)d_in[9];
    const float* bV = (const float*)d_in[10];
    const float* Wx = (const float*)d_in[11];
    const float* Wh = (const float*)d_in[12];
    const float* b_lstm = (const float*)d_in[13];
    const float* Wd = (const float*)d_in[14];
    const float* bd = (const float*)d_in[15];
    float* out = (float*)d_out;
    float* ws = (float*)d_ws;

    unsigned short* keys16 = (unsigned short*)(ws + OFF_KEYS);
    float* xT = ws + OFF_XT;
    float* ws_h = ws + OFF_H;
    float* ws_c = ws + OFF_C;
    float* ws_rs = ws + OFF_RS;
    unsigned short* Hb = (unsigned short*)(ws + OFF_HBUF);
    unsigned short* wdT = (unsigned short*)(ws + OFF_WDT);

    init_kernel<<<16, 256, 0, stream>>>(h0, c0, ws_h, ws_c, xT, ws_rs);
    keys_kernel<<<256, 256, 0, stream>>>(enc, W2, b2, keys16);
    for (int t = 0; t < NT; t++) {
        att_kernel<<<16, 256, 0, stream>>>(t, dec, emb, W1, b1, Va, bV, enc, keys16, ws_h, xT);
        lstm_kernel<<<64, 256, 0, stream>>>(t, Wx, Wh, b_lstm, xT, ws_h, ws_c, Hb);
    }
    wdtile_kernel<<<4000, 256, 0, stream>>>(Wd, wdT);
    gemm_kernel<<<2000, 256, 0, stream>>>(Hb, wdT, bd, out, ws_rs);
    scale_kernel<<<1024, 256, 0, stream>>>(out, ws_rs);
}

// Round 4
// 3383.083 us; speedup vs baseline: 2.1656x; 2.0239x over previous
//
#include <hip/hip_runtime.h>

// Decoder, B=16, T=64, S=128, D_ENC=512, U=256, V=32000.
// Round 4: persistent recurrence kernel (all 64 steps, custom grid barrier),
// then one bf16 MFMA vocab GEMM + exp + rowsum, deferred softmax scale.

#define NB 16
#define NT 64
#define NS 128
#define DE 512
#define NU 256
#define NV 32000
#define NBLK 256

// ws layout (floats); total 4,580,368 fl = 18.32 MB (harness proven >= 18.53 MB)
static const size_t OFF_KEYS = 0;         // keysT bf16 [16][256][128] = 262144 fl
static const size_t OFF_XT   = 262144;    // xT [1024][16] fp32 (rows 0-767 x, 768-1023 h)
static const size_t OFF_C    = 278528;    // c dbuf [2][16][256]
static const size_t OFF_ZP   = 286720;    // zp [4][16][1024]
static const size_t OFF_RS   = 352256;    // rowsums [1024]
static const size_t OFF_BAR  = 353280;    // grid barrier counter (int)
static const size_t OFF_HBUF = 353296;    // Hb fragment-tiled bf16 = 131072 fl
static const size_t OFF_WDT  = 484368;    // wdT fragment-tiled bf16 = 4096000 fl

typedef __attribute__((ext_vector_type(8))) short bf16x8;
typedef __attribute__((ext_vector_type(4))) float f32x4;

__device__ __forceinline__ float bf2f(unsigned int us) { return __uint_as_float(us << 16); }
__device__ __forceinline__ unsigned short f2bf(float f) {
    unsigned int u = __float_as_uint(f);
    return (unsigned short)((u + 0x7fffu + ((u >> 16) & 1u)) >> 16);
}
__device__ __forceinline__ float rcp_fast(float x) { return __builtin_amdgcn_rcpf(x); }
__device__ __forceinline__ float sigm(float x) { return rcp_fast(1.0f + __expf(-x)); }
__device__ __forceinline__ float tanh1(float x) {
    float e = __expf(2.0f * x);
    return 1.0f - 2.0f * rcp_fast(e + 1.0f);
}

// device-scope grid barrier: monotonic counter, agent fences for cross-XCD visibility
__device__ __forceinline__ void gbar(int* bar, int need) {
    __syncthreads();
    if (threadIdx.x == 0) {
        __builtin_amdgcn_fence(__ATOMIC_RELEASE, "agent");
        __hip_atomic_fetch_add(bar, 1, __ATOMIC_RELAXED, __HIP_MEMORY_SCOPE_AGENT);
        while (__hip_atomic_load(bar, __ATOMIC_RELAXED, __HIP_MEMORY_SCOPE_AGENT) < need * NBLK) {
            __builtin_amdgcn_s_sleep(2);
        }
        __builtin_amdgcn_fence(__ATOMIC_ACQUIRE, "agent");
    }
    __syncthreads();
}

// ---------------- init: c buf0, xT h rows, rs, barrier ----------------
__launch_bounds__(256)
__global__ void init_kernel(const float* __restrict__ h0, const float* __restrict__ c0,
                            float* __restrict__ cbuf, float* __restrict__ xT,
                            float* __restrict__ rs, int* __restrict__ bar) {
    int b = blockIdx.x, u = threadIdx.x;
    cbuf[b * NU + u] = c0[b * NU + u];
    xT[(768 + u) * NB + b] = h0[b * NU + u];
    if (u < 64) rs[b * 64 + u] = 0.f;
    if (b == 0 && u == 0) bar[0] = 0;
}

// ---------------- keys^T = (enc @ W2 + b2)^T  -> keysT[b][u][s] bf16 ----------------
__launch_bounds__(256)
__global__ void keys_kernel(const float* __restrict__ enc, const float* __restrict__ W2,
                            const float* __restrict__ b2, unsigned short* __restrict__ keysT) {
    __shared__ float els[8 * DE];  // 16 KB
    int b = blockIdx.x >> 4, so = blockIdx.x & 15;
    int u = threadIdx.x;
    const float4* src = (const float4*)(enc + ((size_t)b * NS + so * 8) * DE);
    float4* dst = (float4*)els;
    for (int i = u; i < 8 * DE / 4; i += 256) dst[i] = src[i];
    __syncthreads();
    float bias = b2[u];
    float acc[8];
#pragma unroll
    for (int ss = 0; ss < 8; ss++) acc[ss] = bias;
#pragma unroll 4
    for (int d = 0; d < DE; d++) {
        float w = W2[d * NU + u];
#pragma unroll
        for (int ss = 0; ss < 8; ss++) acc[ss] = fmaf(els[ss * DE + d], w, acc[ss]);
    }
    // thread owns (u, 8 consecutive s) -> 16B contiguous store in keysT
    unsigned int w0 = (unsigned int)f2bf(acc[0]) | ((unsigned int)f2bf(acc[1]) << 16);
    unsigned int w1 = (unsigned int)f2bf(acc[2]) | ((unsigned int)f2bf(acc[3]) << 16);
    unsigned int w2 = (unsigned int)f2bf(acc[4]) | ((unsigned int)f2bf(acc[5]) << 16);
    unsigned int w3 = (unsigned int)f2bf(acc[6]) | ((unsigned int)f2bf(acc[7]) << 16);
    *(uint4*)(keysT + ((size_t)b * NU + u) * NS + so * 8) = make_uint4(w0, w1, w2, w3);
}

// ---------------- Wd -> fragment-tiled bf16 ----------------
__launch_bounds__(256)
__global__ void wdtile_kernel(const float* __restrict__ Wd, unsigned short* __restrict__ wdT) {
    int id = blockIdx.x * 256 + threadIdx.x;  // 0 .. 1,023,999
    int l = id & 63, c16 = (id >> 6) & 7, ks = (id >> 9) & 7, p = id >> 12;
    int v = p * 128 + c16 * 16 + (l & 15);
    int k0 = ks * 32 + (l >> 4) * 8;
    unsigned int wout[4];
#pragma unroll
    for (int jj = 0; jj < 4; jj++) {
        unsigned int lo = f2bf(Wd[(size_t)(k0 + 2 * jj) * NV + v]);
        unsigned int hi = f2bf(Wd[(size_t)(k0 + 2 * jj + 1) * NV + v]);
        wout[jj] = lo | (hi << 16);
    }
    *(uint4*)(wdT + (size_t)id * 8) = make_uint4(wout[0], wout[1], wout[2], wout[3]);
}

// ---------------- persistent recurrence: 64 steps, 2 phases/step ----------------
__launch_bounds__(256, 1)
__global__ void recur_kernel(const int* __restrict__ dec, const float* __restrict__ enc,
                             const float* __restrict__ emb, const float* __restrict__ W1,
                             const float* __restrict__ b1, const float* __restrict__ Va,
                             const float* __restrict__ bV, const float* __restrict__ Wx,
                             const float* __restrict__ Wh, const float* __restrict__ b_lstm,
                             const float* __restrict__ h0,
                             const unsigned short* __restrict__ keysT, float* __restrict__ xT,
                             float* __restrict__ cbuf, float* __restrict__ zp,
                             unsigned short* __restrict__ Hb, int* __restrict__ bar) {
    __shared__ float smem[4352];  // B: xs[256][17]; A: hl|qv|scp|red|attn
    int blk = blockIdx.x, tid = threadIdx.x;
    int nbar = 0;

    for (int it = 0; it <= NT; ++it) {
        // ---------- phase A: gates (it>0) + attention (it<NT) on blocks 0..63 ----------
        if (blk < 64) {
            int b = blk >> 2, q = blk & 3;
            float* hl = smem;
            float* qv = smem + 256;
            float* scp = smem + 512;
            float* red = smem + 768;
            float* attn = smem + 896;
            int u = tid;
            float hn;
            if (it > 0) {
                const float* zpb = zp + b * 1024 + u;
                float zg4[4];
#pragma unroll
                for (int g = 0; g < 4; g++) {
                    zg4[g] = b_lstm[g * 256 + u] + zpb[0 * 16384 + g * 256] +
                             zpb[1 * 16384 + g * 256] + zpb[2 * 16384 + g * 256] +
                             zpb[3 * 16384 + g * 256];
                }
                float cold = cbuf[((it - 1) & 1) * 4096 + b * NU + u];
                float cn = sigm(zg4[1]) * cold + sigm(zg4[0]) * tanh1(zg4[2]);
                hn = sigm(zg4[3]) * tanh1(cn);
                if (q == 0) {
                    cbuf[(it & 1) * 4096 + b * NU + u] = cn;
                    xT[(768 + u) * NB + b] = hn;
                    int r = (it - 1) * NB + b;
                    int mp = r >> 7, lr = r & 127;
                    int chunk = ((u >> 5) * 8 + (lr >> 4)) * 64 + ((u >> 3) & 3) * 16 + (lr & 15);
                    Hb[(size_t)mp * 32768 + chunk * 8 + (u & 7)] = f2bf(hn);
                }
            } else {
                hn = h0[b * NU + u];
            }
            hl[u] = hn;
            __syncthreads();
            if (it < NT) {
                // q = h @ W1 + b1 (full, replicated across the 4 q-blocks)
                float a = b1[u];
#pragma unroll 4
                for (int d = 0; d < NU; d++) a = fmaf(hl[d], W1[d * NU + u], a);
                qv[u] = a;
                __syncthreads();
                // scores (full 128 rows, replicated): thread = (s, u-half)
                int s = tid & 127, uh = tid >> 7;
                const unsigned short* kp = keysT + ((size_t)b * NU + uh * 128) * NS + s;
                float sc = 0.f;
#pragma unroll 4
                for (int uu = 0; uu < 128; uu++)
                    sc = fmaf(tanh1(qv[uh * 128 + uu] + bf2f(kp[(size_t)uu * NS])),
                              Va[uh * 128 + uu], sc);
                scp[uh * NS + s] = sc;
                __syncthreads();
                float scfull = 0.f, p = 0.f;
                if (tid < NS) {
                    scfull = scp[tid] + scp[NS + tid] + bV[0];
                    red[tid] = scfull;
                }
                __syncthreads();
                for (int off = 64; off >= 1; off >>= 1) {
                    if (tid < off) red[tid] = fmaxf(red[tid], red[tid + off]);
                    __syncthreads();
                }
                float m = red[0];
                __syncthreads();
                if (tid < NS) {
                    p = __expf(scfull - m);
                    red[tid] = p;
                }
                __syncthreads();
                for (int off = 64; off >= 1; off >>= 1) {
                    if (tid < off) red[tid] += red[tid + off];
                    __syncthreads();
                }
                float tot = red[0];
                if (tid < NS) attn[tid] = p / tot;
                __syncthreads();
                // ctx quarter: d = q*128 + (tid&127), s-half = tid>>7
                int dl = tid & 127, sh = tid >> 7;
                const float* ep = enc + ((size_t)b * NS + sh * 64) * DE + q * 128 + dl;
                float cp = 0.f;
#pragma unroll 4
                for (int i2 = 0; i2 < 64; i2++) cp = fmaf(attn[sh * 64 + i2], ep[(size_t)i2 * DE], cp);
                scp[sh * 128 + dl] = cp;
                __syncthreads();
                if (tid < 128) xT[(q * 128 + tid) * NB + b] = scp[tid] + scp[128 + tid];
                if (q == 3) {
                    int tok = dec[b * NT + it];
                    tok = (tok < 0) ? 0 : (tok >= NV ? NV - 1 : tok);
                    xT[(512 + u) * NB + b] = emb[(size_t)tok * NU + u];
                }
            }
        }
        gbar(bar, ++nbar);
        if (it == NT) break;

        // ---------- phase B: z partials, all 256 blocks = 64 j-groups x 4 k-quarters ----------
        {
            int jg = blk >> 2, kq = blk & 3;
            float* xs = smem;  // [256][17]
            const float4* s4 = (const float4*)(xT + (kq * 256 + tid) * NB);
            float4 v0 = s4[0], v1 = s4[1], v2 = s4[2], v3 = s4[3];
            float* xd = xs + tid * 17;
            xd[0] = v0.x; xd[1] = v0.y; xd[2] = v0.z; xd[3] = v0.w;
            xd[4] = v1.x; xd[5] = v1.y; xd[6] = v1.z; xd[7] = v1.w;
            xd[8] = v2.x; xd[9] = v2.y; xd[10] = v2.z; xd[11] = v2.w;
            xd[12] = v3.x; xd[13] = v3.y; xd[14] = v3.z; xd[15] = v3.w;
            __syncthreads();
            int jl = tid & 15, b = tid >> 4;
            int j = jg * 16 + jl;
            const float* wp = (kq < 3) ? (Wx + (size_t)(kq * 256) * 1024 + j) : (Wh + j);
            float a0 = 0.f, a1 = 0.f, a2 = 0.f, a3 = 0.f;
#pragma unroll 4
            for (int i2 = 0; i2 < 256; i2 += 4) {
                a0 = fmaf(wp[(size_t)(i2 + 0) * 1024], xs[(i2 + 0) * 17 + b], a0);
                a1 = fmaf(wp[(size_t)(i2 + 1) * 1024], xs[(i2 + 1) * 17 + b], a1);
                a2 = fmaf(wp[(size_t)(i2 + 2) * 1024], xs[(i2 + 2) * 17 + b], a2);
                a3 = fmaf(wp[(size_t)(i2 + 3) * 1024], xs[(i2 + 3) * 17 + b], a3);
            }
            zp[(kq * 16 + b) * 1024 + j] = (a0 + a1) + (a2 + a3);
        }
        gbar(bar, ++nbar);
    }
}

// ---------------- batched vocab GEMM + exp + rowsum ----------------
__launch_bounds__(256)
__global__ void gemm_kernel(const unsigned short* __restrict__ Hb,
                            const unsigned short* __restrict__ wdT,
                            const float* __restrict__ bd, float* __restrict__ out,
                            float* __restrict__ rs) {
    int w = (blockIdx.x & 7) * 250 + (blockIdx.x >> 3);
    int np = w >> 3, mp = w & 7;
    int wave = threadIdx.x >> 6, l = threadIdx.x & 63;
    int wm = wave >> 1, wn = wave & 1;
    const bf16x8* A = (const bf16x8*)Hb + (size_t)mp * 4096;
    const bf16x8* B = (const bf16x8*)wdT + (size_t)np * 4096;
    f32x4 acc[4][4];
#pragma unroll
    for (int mf = 0; mf < 4; mf++)
#pragma unroll
        for (int nf = 0; nf < 4; nf++) acc[mf][nf] = (f32x4){0.f, 0.f, 0.f, 0.f};
#pragma unroll
    for (int ks = 0; ks < 8; ks++) {
        bf16x8 av[4], bv[4];
#pragma unroll
        for (int mf = 0; mf < 4; mf++) av[mf] = A[(ks * 8 + wm * 4 + mf) * 64 + l];
#pragma unroll
        for (int nf = 0; nf < 4; nf++) bv[nf] = B[(ks * 8 + wn * 4 + nf) * 64 + l];
#pragma unroll
        for (int mf = 0; mf < 4; mf++)
#pragma unroll
            for (int nf = 0; nf < 4; nf++)
                acc[mf][nf] =
                    __builtin_amdgcn_mfma_f32_16x16x32_bf16(av[mf], bv[nf], acc[mf][nf], 0, 0, 0);
    }
    int colg = np * 128 + wn * 64;
    int rowg = mp * 128 + wm * 64;
#pragma unroll
    for (int mf = 0; mf < 4; mf++) {
        float rloc[4] = {0.f, 0.f, 0.f, 0.f};
#pragma unroll
        for (int nf = 0; nf < 4; nf++) {
            int col = colg + nf * 16 + (l & 15);
            float bdv = bd[col];
#pragma unroll
            for (int reg = 0; reg < 4; reg++) {
                int r = rowg + mf * 16 + (l >> 4) * 4 + reg;  // r = t*16 + b
                float p = __expf(acc[mf][nf][reg] + bdv);
                out[(size_t)((r & 15) * NT + (r >> 4)) * NV + col] = p;
                rloc[reg] += p;
            }
        }
#pragma unroll
        for (int reg = 0; reg < 4; reg++) {
            float v = rloc[reg];
            v += __shfl_xor(v, 1);
            v += __shfl_xor(v, 2);
            v += __shfl_xor(v, 4);
            v += __shfl_xor(v, 8);
            if ((l & 15) == 0) atomicAdd(&rs[rowg + mf * 16 + (l >> 4) * 4 + reg], v);
        }
    }
}

// ---------------- final softmax normalization ----------------
__launch_bounds__(256)
__global__ void scale_kernel(float* __restrict__ out, const float* __restrict__ rs) {
    int o = blockIdx.x;  // out row = b*64 + t
    int b = o >> 6, t = o & 63;
    float rinv = 1.0f / rs[t * NB + b];
    float4* op = (float4*)(out + (size_t)o * NV);
    for (int i = threadIdx.x; i < NV / 4; i += 256) {
        float4 v = op[i];
        v.x *= rinv; v.y *= rinv; v.z *= rinv; v.w *= rinv;
        op[i] = v;
    }
}

extern "C" void kernel_launch(void* const* d_in, const int* in_sizes, int n_in,
                              void* d_out, int out_size, void* d_ws, size_t ws_size,
                              hipStream_t stream) {
    const int* dec = (const int*)d_in[0];
    const float* enc = (const float*)d_in[1];
    const float* h0 = (const float*)d_in[2];
    const float* c0 = (const float*)d_in[3];
    const float* emb = (const float*)d_in[4];
    const float* W1 = (const float*)d_in[5];
    const float* b1 = (const float*)d_in[6];
    const float* W2 = (const float*)d_in[7];
    const float* b2 = (const float*)d_in[8];
    const float* Va = (const float*)d_in[9];
    const float* bV = (const float*)d_in[10];
    const float* Wx = (const float*)d_in[11];
    const float* Wh = (const float*)d_in[12];
    const float* b_lstm = (const float*)d_in[13];
    const float* Wd = (const float*)d_in[14];
    const float* bd = (const float*)d_in[15];
    float* out = (float*)d_out;
    float* ws = (float*)d_ws;

    unsigned short* keysT = (unsigned short*)(ws + OFF_KEYS);
    float* xT = ws + OFF_XT;
    float* cbuf = ws + OFF_C;
    float* zp = ws + OFF_ZP;
    float* ws_rs = ws + OFF_RS;
    int* bar = (int*)(ws + OFF_BAR);
    unsigned short* Hb = (unsigned short*)(ws + OFF_HBUF);
    unsigned short* wdT = (unsigned short*)(ws + OFF_WDT);

    init_kernel<<<16, 256, 0, stream>>>(h0, c0, cbuf, xT, ws_rs, bar);
    keys_kernel<<<256, 256, 0, stream>>>(enc, W2, b2, keysT);
    wdtile_kernel<<<4000, 256, 0, stream>>>(Wd, wdT);
    recur_kernel<<<NBLK, 256, 0, stream>>>(dec, enc, emb, W1, b1, Va, bV, Wx, Wh, b_lstm,
                                           h0, keysT, xT, cbuf, zp, Hb, bar);
    gemm_kernel<<<2000, 256, 0, stream>>>(Hb, wdT, bd, out, ws_rs);
    scale_kernel<<<1024, 256, 0, stream>>>(out, ws_rs);
}

// Round 5
// 2402.359 us; speedup vs baseline: 3.0496x; 1.4082x over previous
//
#include <hip/hip_runtime.h>

// Decoder, B=16, T=64, S=128, D_ENC=512, U=256, V=32000.
// Round 5: persistent recurrence with FENCE-FREE grid barrier.
//   - cross-phase data (zp, xT) uses agent-scope relaxed atomics (sc0/sc1,
//     coherent at L3) so the barrier needs no L2-invalidating fences
//   - read-only weights stay warm in per-XCD L2 across all 128 phases
//   - LSTM cell state c lives in registers (every (b,q) replica recomputes it)
// Epilogue: one bf16 MFMA vocab GEMM + exp + rowsum, deferred softmax scale.

#define NB 16
#define NT 64
#define NS 128
#define DE 512
#define NU 256
#define NV 32000
#define NBLK 256

// ws layout (floats); total <= 18.32 MB (harness proven >= 18.53 MB)
static const size_t OFF_KEYS = 0;         // keysT bf16 [16][256][128] = 262144 fl
static const size_t OFF_XT   = 262144;    // xT [1024][16] fp32 (rows 0-767 x, 768-1023 h)
static const size_t OFF_C    = 278528;    // (unused this round)
static const size_t OFF_ZP   = 286720;    // zp [4][16][1024]
static const size_t OFF_RS   = 352256;    // rowsums [1024]
static const size_t OFF_BAR  = 353280;    // grid barrier counter (int)
static const size_t OFF_HBUF = 353296;    // Hb fragment-tiled bf16 = 131072 fl
static const size_t OFF_WDT  = 484368;    // wdT fragment-tiled bf16 = 4096000 fl

typedef __attribute__((ext_vector_type(8))) short bf16x8;
typedef __attribute__((ext_vector_type(4))) float f32x4;

__device__ __forceinline__ float bf2f(unsigned int us) { return __uint_as_float(us << 16); }
__device__ __forceinline__ unsigned short f2bf(float f) {
    unsigned int u = __float_as_uint(f);
    return (unsigned short)((u + 0x7fffu + ((u >> 16) & 1u)) >> 16);
}
__device__ __forceinline__ float rcp_fast(float x) { return __builtin_amdgcn_rcpf(x); }
__device__ __forceinline__ float sigm(float x) { return rcp_fast(1.0f + __expf(-x)); }
__device__ __forceinline__ float tanh1(float x) {
    float e = __expf(2.0f * x);
    return 1.0f - 2.0f * rcp_fast(e + 1.0f);
}

// coherent (L3-point) accesses for cross-phase data: bypass non-coherent L2
__device__ __forceinline__ void cstore(float* p, float v) {
    __hip_atomic_store(p, v, __ATOMIC_RELAXED, __HIP_MEMORY_SCOPE_AGENT);
}
__device__ __forceinline__ float cload(const float* p) {
    return __hip_atomic_load(p, __ATOMIC_RELAXED, __HIP_MEMORY_SCOPE_AGENT);
}

// fence-free grid barrier: each wave's vmcnt is drained by __syncthreads'
// implicit waitcnt, so sc0/sc1 stores are already visible at L3 on arrival.
// Control dependence + in-order issue order the post-barrier coherent loads.
__device__ __forceinline__ void gbar(int* bar, int need) {
    __syncthreads();
    if (threadIdx.x == 0) {
        asm volatile("s_waitcnt vmcnt(0) lgkmcnt(0)" ::: "memory");
        __hip_atomic_fetch_add(bar, 1, __ATOMIC_RELAXED, __HIP_MEMORY_SCOPE_AGENT);
        while (__hip_atomic_load(bar, __ATOMIC_RELAXED, __HIP_MEMORY_SCOPE_AGENT) < need) {
            __builtin_amdgcn_s_sleep(8);
        }
        asm volatile("" ::: "memory");
    }
    __syncthreads();
}

// ---------------- init: xT h rows, rs, barrier ----------------
__launch_bounds__(256)
__global__ void init_kernel(const float* __restrict__ h0, float* __restrict__ xT,
                            float* __restrict__ rs, int* __restrict__ bar) {
    int b = blockIdx.x, u = threadIdx.x;
    xT[(768 + u) * NB + b] = h0[b * NU + u];
    if (u < 64) rs[b * 64 + u] = 0.f;
    if (b == 0 && u == 0) bar[0] = 0;
}

// ---------------- keys^T = (enc @ W2 + b2)^T  -> keysT[b][u][s] bf16 ----------------
__launch_bounds__(256)
__global__ void keys_kernel(const float* __restrict__ enc, const float* __restrict__ W2,
                            const float* __restrict__ b2, unsigned short* __restrict__ keysT) {
    __shared__ float els[8 * DE];  // 16 KB
    int b = blockIdx.x >> 4, so = blockIdx.x & 15;
    int u = threadIdx.x;
    const float4* src = (const float4*)(enc + ((size_t)b * NS + so * 8) * DE);
    float4* dst = (float4*)els;
    for (int i = u; i < 8 * DE / 4; i += 256) dst[i] = src[i];
    __syncthreads();
    float bias = b2[u];
    float acc[8];
#pragma unroll
    for (int ss = 0; ss < 8; ss++) acc[ss] = bias;
#pragma unroll 4
    for (int d = 0; d < DE; d++) {
        float w = W2[d * NU + u];
#pragma unroll
        for (int ss = 0; ss < 8; ss++) acc[ss] = fmaf(els[ss * DE + d], w, acc[ss]);
    }
    unsigned int w0 = (unsigned int)f2bf(acc[0]) | ((unsigned int)f2bf(acc[1]) << 16);
    unsigned int w1 = (unsigned int)f2bf(acc[2]) | ((unsigned int)f2bf(acc[3]) << 16);
    unsigned int w2 = (unsigned int)f2bf(acc[4]) | ((unsigned int)f2bf(acc[5]) << 16);
    unsigned int w3 = (unsigned int)f2bf(acc[6]) | ((unsigned int)f2bf(acc[7]) << 16);
    *(uint4*)(keysT + ((size_t)b * NU + u) * NS + so * 8) = make_uint4(w0, w1, w2, w3);
}

// ---------------- Wd -> fragment-tiled bf16 ----------------
__launch_bounds__(256)
__global__ void wdtile_kernel(const float* __restrict__ Wd, unsigned short* __restrict__ wdT) {
    int id = blockIdx.x * 256 + threadIdx.x;  // 0 .. 1,023,999
    int l = id & 63, c16 = (id >> 6) & 7, ks = (id >> 9) & 7, p = id >> 12;
    int v = p * 128 + c16 * 16 + (l & 15);
    int k0 = ks * 32 + (l >> 4) * 8;
    unsigned int wout[4];
#pragma unroll
    for (int jj = 0; jj < 4; jj++) {
        unsigned int lo = f2bf(Wd[(size_t)(k0 + 2 * jj) * NV + v]);
        unsigned int hi = f2bf(Wd[(size_t)(k0 + 2 * jj + 1) * NV + v]);
        wout[jj] = lo | (hi << 16);
    }
    *(uint4*)(wdT + (size_t)id * 8) = make_uint4(wout[0], wout[1], wout[2], wout[3]);
}

// ---------------- persistent recurrence: 64 steps, 2 phases/step ----------------
__launch_bounds__(256, 1)
__global__ void recur_kernel(const int* __restrict__ dec, const float* __restrict__ enc,
                             const float* __restrict__ emb, const float* __restrict__ W1,
                             const float* __restrict__ b1, const float* __restrict__ Va,
                             const float* __restrict__ bV, const float* __restrict__ Wx,
                             const float* __restrict__ Wh, const float* __restrict__ b_lstm,
                             const float* __restrict__ h0, const float* __restrict__ c0,
                             const unsigned short* __restrict__ keysT, float* __restrict__ xT,
                             float* __restrict__ zp, unsigned short* __restrict__ Hb,
                             int* __restrict__ bar) {
    __shared__ float smem[4352];  // B: xs[256][17]; A: hl|qv|scp|red|attn
    int blk = blockIdx.x, tid = threadIdx.x;
    int nbar = 0;
    int ab = blk >> 2, aq = blk & 3;  // phase-A role: batch, quarter
    // LSTM cell state in registers (each (b,q) replica maintains its own copy)
    float c_reg = (blk < 64) ? c0[ab * NU + tid] : 0.f;

    for (int it = 0; it <= NT; ++it) {
        // ---------- phase A: gates (it>0) + attention (it<NT) on blocks 0..63 ----------
        if (blk < 64) {
            int b = ab, q = aq;
            float* hl = smem;
            float* qv = smem + 256;
            float* scp = smem + 512;
            float* red = smem + 768;
            float* attn = smem + 896;
            int u = tid;
            float hn;
            if (it > 0) {
                const float* zpb = zp + b * 1024 + u;
                float zg4[4];
#pragma unroll
                for (int g = 0; g < 4; g++) {
                    zg4[g] = b_lstm[g * 256 + u] + cload(zpb + 0 * 16384 + g * 256) +
                             cload(zpb + 1 * 16384 + g * 256) +
                             cload(zpb + 2 * 16384 + g * 256) +
                             cload(zpb + 3 * 16384 + g * 256);
                }
                float cn = sigm(zg4[1]) * c_reg + sigm(zg4[0]) * tanh1(zg4[2]);
                c_reg = cn;
                hn = sigm(zg4[3]) * tanh1(cn);
                if (q == 0) {
                    cstore(&xT[(768 + u) * NB + b], hn);
                    int r = (it - 1) * NB + b;
                    int mp = r >> 7, lr = r & 127;
                    int chunk = ((u >> 5) * 8 + (lr >> 4)) * 64 + ((u >> 3) & 3) * 16 + (lr & 15);
                    Hb[(size_t)mp * 32768 + chunk * 8 + (u & 7)] = f2bf(hn);
                }
            } else {
                hn = h0[b * NU + u];
            }
            hl[u] = hn;
            __syncthreads();
            if (it < NT) {
                // q = h @ W1 + b1 (replicated across the 4 q-blocks)
                float a = b1[u];
#pragma unroll 4
                for (int d = 0; d < NU; d++) a = fmaf(hl[d], W1[d * NU + u], a);
                qv[u] = a;
                __syncthreads();
                // scores: thread = (s, u-half)
                int s = tid & 127, uh = tid >> 7;
                const unsigned short* kp = keysT + ((size_t)b * NU + uh * 128) * NS + s;
                float sc = 0.f;
#pragma unroll 4
                for (int uu = 0; uu < 128; uu++)
                    sc = fmaf(tanh1(qv[uh * 128 + uu] + bf2f(kp[(size_t)uu * NS])),
                              Va[uh * 128 + uu], sc);
                scp[uh * NS + s] = sc;
                __syncthreads();
                float scfull = 0.f, p = 0.f;
                if (tid < NS) {
                    scfull = scp[tid] + scp[NS + tid] + bV[0];
                    red[tid] = scfull;
                }
                __syncthreads();
                for (int off = 64; off >= 1; off >>= 1) {
                    if (tid < off) red[tid] = fmaxf(red[tid], red[tid + off]);
                    __syncthreads();
                }
                float m = red[0];
                __syncthreads();
                if (tid < NS) {
                    p = __expf(scfull - m);
                    red[tid] = p;
                }
                __syncthreads();
                for (int off = 64; off >= 1; off >>= 1) {
                    if (tid < off) red[tid] += red[tid + off];
                    __syncthreads();
                }
                float tot = red[0];
                if (tid < NS) attn[tid] = p / tot;
                __syncthreads();
                // ctx quarter: d = q*128 + (tid&127), s-half = tid>>7
                int dl = tid & 127, sh = tid >> 7;
                const float* ep = enc + ((size_t)b * NS + sh * 64) * DE + q * 128 + dl;
                float cp = 0.f;
#pragma unroll 4
                for (int i2 = 0; i2 < 64; i2++)
                    cp = fmaf(attn[sh * 64 + i2], ep[(size_t)i2 * DE], cp);
                scp[sh * 128 + dl] = cp;
                __syncthreads();
                if (tid < 128) cstore(&xT[(q * 128 + tid) * NB + b], scp[tid] + scp[128 + tid]);
                if (q == 3) {
                    int tok = dec[b * NT + it];
                    tok = (tok < 0) ? 0 : (tok >= NV ? NV - 1 : tok);
                    cstore(&xT[(512 + u) * NB + b], emb[(size_t)tok * NU + u]);
                }
            }
        }
        gbar(bar, (++nbar) * NBLK);
        if (it == NT) break;

        // ---------- phase B: z partials, 256 blocks = 64 j-groups x 4 k-quarters ----------
        {
            int jg = blk >> 2, kq = blk & 3;
            float* xs = smem;  // [256][17]
            const float* srow = xT + (kq * 256 + tid) * NB;
            float* xd = xs + tid * 17;
#pragma unroll
            for (int i = 0; i < 16; i++) xd[i] = cload(srow + i);
            __syncthreads();
            int jl = tid & 15, b = tid >> 4;
            int j = jg * 16 + jl;
            const float* wp = (kq < 3) ? (Wx + (size_t)(kq * 256) * 1024 + j) : (Wh + j);
            float a0 = 0.f, a1 = 0.f, a2 = 0.f, a3 = 0.f;
#pragma unroll 4
            for (int i2 = 0; i2 < 256; i2 += 4) {
                a0 = fmaf(wp[(size_t)(i2 + 0) * 1024], xs[(i2 + 0) * 17 + b], a0);
                a1 = fmaf(wp[(size_t)(i2 + 1) * 1024], xs[(i2 + 1) * 17 + b], a1);
                a2 = fmaf(wp[(size_t)(i2 + 2) * 1024], xs[(i2 + 2) * 17 + b], a2);
                a3 = fmaf(wp[(size_t)(i2 + 3) * 1024], xs[(i2 + 3) * 17 + b], a3);
            }
            cstore(&zp[(kq * 16 + b) * 1024 + j], (a0 + a1) + (a2 + a3));
            __syncthreads();
        }
        gbar(bar, (++nbar) * NBLK);
    }
}

// ---------------- batched vocab GEMM + exp + rowsum ----------------
__launch_bounds__(256)
__global__ void gemm_kernel(const unsigned short* __restrict__ Hb,
                            const unsigned short* __restrict__ wdT,
                            const float* __restrict__ bd, float* __restrict__ out,
                            float* __restrict__ rs) {
    int w = (blockIdx.x & 7) * 250 + (blockIdx.x >> 3);
    int np = w >> 3, mp = w & 7;
    int wave = threadIdx.x >> 6, l = threadIdx.x & 63;
    int wm = wave >> 1, wn = wave & 1;
    const bf16x8* A = (const bf16x8*)Hb + (size_t)mp * 4096;
    const bf16x8* B = (const bf16x8*)wdT + (size_t)np * 4096;
    f32x4 acc[4][4];
#pragma unroll
    for (int mf = 0; mf < 4; mf++)
#pragma unroll
        for (int nf = 0; nf < 4; nf++) acc[mf][nf] = (f32x4){0.f, 0.f, 0.f, 0.f};
#pragma unroll
    for (int ks = 0; ks < 8; ks++) {
        bf16x8 av[4], bv[4];
#pragma unroll
        for (int mf = 0; mf < 4; mf++) av[mf] = A[(ks * 8 + wm * 4 + mf) * 64 + l];
#pragma unroll
        for (int nf = 0; nf < 4; nf++) bv[nf] = B[(ks * 8 + wn * 4 + nf) * 64 + l];
#pragma unroll
        for (int mf = 0; mf < 4; mf++)
#pragma unroll
            for (int nf = 0; nf < 4; nf++)
                acc[mf][nf] =
                    __builtin_amdgcn_mfma_f32_16x16x32_bf16(av[mf], bv[nf], acc[mf][nf], 0, 0, 0);
    }
    int colg = np * 128 + wn * 64;
    int rowg = mp * 128 + wm * 64;
#pragma unroll
    for (int mf = 0; mf < 4; mf++) {
        float rloc[4] = {0.f, 0.f, 0.f, 0.f};
#pragma unroll
        for (int nf = 0; nf < 4; nf++) {
            int col = colg + nf * 16 + (l & 15);
            float bdv = bd[col];
#pragma unroll
            for (int reg = 0; reg < 4; reg++) {
                int r = rowg + mf * 16 + (l >> 4) * 4 + reg;  // r = t*16 + b
                float p = __expf(acc[mf][nf][reg] + bdv);
                out[(size_t)((r & 15) * NT + (r >> 4)) * NV + col] = p;
                rloc[reg] += p;
            }
        }
#pragma unroll
        for (int reg = 0; reg < 4; reg++) {
            float v = rloc[reg];
            v += __shfl_xor(v, 1);
            v += __shfl_xor(v, 2);
            v += __shfl_xor(v, 4);
            v += __shfl_xor(v, 8);
            if ((l & 15) == 0) atomicAdd(&rs[rowg + mf * 16 + (l >> 4) * 4 + reg], v);
        }
    }
}

// ---------------- final softmax normalization ----------------
__launch_bounds__(256)
__global__ void scale_kernel(float* __restrict__ out, const float* __restrict__ rs) {
    int o = blockIdx.x;  // out row = b*64 + t
    int b = o >> 6, t = o & 63;
    float rinv = 1.0f / rs[t * NB + b];
    float4* op = (float4*)(out + (size_t)o * NV);
    for (int i = threadIdx.x; i < NV / 4; i += 256) {
        float4 v = op[i];
        v.x *= rinv; v.y *= rinv; v.z *= rinv; v.w *= rinv;
        op[i] = v;
    }
}

extern "C" void kernel_launch(void* const* d_in, const int* in_sizes, int n_in,
                              void* d_out, int out_size, void* d_ws, size_t ws_size,
                              hipStream_t stream) {
    const int* dec = (const int*)d_in[0];
    const float* enc = (const float*)d_in[1];
    const float* h0 = (const float*)d_in[2];
    const float* c0 = (const float*)d_in[3];
    const float* emb = (const float*)d_in[4];
    const float* W1 = (const float*)d_in[5];
    const float* b1 = (const float*)d_in[6];
    const float* W2 = (const float*)d_in[7];
    const float* b2 = (const float*)d_in[8];
    const float* Va = (const float*)d_in[9];
    const float* bV = (const float*)d_in[10];
    const float* Wx = (const float*)d_in[11];
    const float* Wh = (const float*)d_in[12];
    const float* b_lstm = (const float*)d_in[13];
    const float* Wd = (const float*)d_in[14];
    const float* bd = (const float*)d_in[15];
    float* out = (float*)d_out;
    float* ws = (float*)d_ws;

    unsigned short* keysT = (unsigned short*)(ws + OFF_KEYS);
    float* xT = ws + OFF_XT;
    float* zp = ws + OFF_ZP;
    float* ws_rs = ws + OFF_RS;
    int* bar = (int*)(ws + OFF_BAR);
    unsigned short* Hb = (unsigned short*)(ws + OFF_HBUF);
    unsigned short* wdT = (unsigned short*)(ws + OFF_WDT);

    init_kernel<<<16, 256, 0, stream>>>(h0, xT, ws_rs, bar);
    keys_kernel<<<256, 256, 0, stream>>>(enc, W2, b2, keysT);
    wdtile_kernel<<<4000, 256, 0, stream>>>(Wd, wdT);
    recur_kernel<<<NBLK, 256, 0, stream>>>(dec, enc, emb, W1, b1, Va, bV, Wx, Wh, b_lstm,
                                           h0, c0, keysT, xT, zp, Hb, bar);
    gemm_kernel<<<2000, 256, 0, stream>>>(Hb, wdT, bd, out, ws_rs);
    scale_kernel<<<1024, 256, 0, stream>>>(out, ws_rs);
}